// Round 7
// baseline (248.444 us; speedup 1.0000x reference)
//
#include <hip/hip_runtime.h>
#include <hip/hip_bf16.h>

#define N_NODES 50000
#define N_EDGES 800000
#define IN_CH 1024
#define OUT_CH 256
#define NBLK 196  // ceil(N_NODES/256)

typedef __attribute__((ext_vector_type(8))) short bf16x8;
typedef __attribute__((ext_vector_type(4))) float f32x4;

__device__ inline unsigned short f2bf(float f) {
  union { float f; unsigned int u; } v; v.f = f;
  unsigned int r = v.u + 0x7fffu + ((v.u >> 16) & 1u);
  return (unsigned short)(r >> 16);
}
__device__ inline float bf2f(unsigned short u) {
  union { unsigned int u; float f; } v; v.u = ((unsigned int)u) << 16;
  return v.f;
}
// pack two f32 -> two bf16 in one u32 (lo = a, hi = b), RNE
__device__ inline unsigned int cvtpk_bf16(float a, float b) {
  unsigned int r;
  asm("v_cvt_pk_bf16_f32 %0, %1, %2" : "=v"(r) : "v"(a), "v"(b));
  return r;
}

// async global->LDS, 16B per lane; LDS dest is wave-uniform base + lane*16
#define GLOAD16(SRC, DST)                                                      \
  __builtin_amdgcn_global_load_lds(                                            \
      (const __attribute__((address_space(1))) void*)(SRC),                    \
      (__attribute__((address_space(3))) void*)(DST), 16, 0, 0)

// blocks [0,256): convert W fp32 -> bf16; blocks [256,...): histogram of tar
__global__ __launch_bounds__(256) void prep_hist(const float* __restrict__ W,
                                                 unsigned short* __restrict__ Wb,
                                                 const int* __restrict__ tar,
                                                 int* __restrict__ counts) {
  const int b = blockIdx.x, t = threadIdx.x;
  if (b < 256) {
    const int i4 = (b * 256 + t) * 4;
    float4 f = *(const float4*)(W + i4);
    *(ushort4*)(Wb + i4) = make_ushort4(f2bf(f.x), f2bf(f.y), f2bf(f.z), f2bf(f.w));
  } else {
    const int e = (b - 256) * 256 + t;
    if (e < N_EDGES) atomicAdd(&counts[tar[e]], 1);
  }
}

// Hb[m][n] = bf16( sum_k X[m][k]*W[n][k] + b[n] )
// m97 structure: 128x128 tile, BK=32, global_load_lds for A (fp32, XOR-swz)
// and B (bf16, 2-bit XOR-swz), dbuf LDS (48KB -> 3 blocks/CU), 1 barrier/step.
// 4 waves (2x2), wave tile 64x64 = 4x4 16x16x32 frags = 16 MFMA/step.
__global__ __launch_bounds__(256, 3) void gemm_proj(
    const float* __restrict__ X, const unsigned short* __restrict__ Wb,
    const float* __restrict__ bias, unsigned short* __restrict__ Hb)
{
  __shared__ float lds_a[2][128][32];           // 32 KB (fp32 A tile)
  __shared__ unsigned short lds_b[2][128][32];  // 16 KB (bf16 B tile)

  const int tid  = threadIdx.x;
  const int lane = tid & 63;
  const int w    = tid >> 6;
  const int wr   = w >> 1, wc = w & 1;
  const int gm0  = blockIdx.x * 128;
  const int gn0  = blockIdx.y * 128;

  f32x4 acc[4][4];
  #pragma unroll
  for (int i = 0; i < 4; i++)
    #pragma unroll
    for (int j = 0; j < 4; j++) acc[i][j] = (f32x4)0.0f;

  // A: 16 wave-loads of 1KB (8 rows x 128B); wave w does wl = 4w..4w+3.
  //    linear dest chunk p = lane&7 at row 8wl+(lane>>3); source chunk
  //    s = p ^ (row&7)  => read back at physical chunk c ^ (row&7).
  // B: 8 wave-loads (16 rows x 64B); wl = 2w..2w+1; p = lane&3,
  //    row = 16wl+(lane>>2); s = p ^ (row&3).
#define STAGE(BUF, K0)                                                         \
  {                                                                            \
    _Pragma("unroll")                                                          \
    for (int q = 0; q < 4; q++) {                                              \
      const int wl   = w * 4 + q;                                              \
      const int row  = 8 * wl + (lane >> 3);                                   \
      const int grow = gm0 + row;                                              \
      const int sc   = (lane & 7) ^ (row & 7);                                 \
      if (grow < N_NODES)                                                      \
        GLOAD16(X + (size_t)grow * IN_CH + (K0) + sc * 4,                      \
                &lds_a[BUF][8 * wl][0]);                                       \
    }                                                                          \
    _Pragma("unroll")                                                          \
    for (int q = 0; q < 2; q++) {                                              \
      const int wl  = w * 2 + q;                                               \
      const int row = 16 * wl + (lane >> 2);                                   \
      const int sc  = (lane & 3) ^ (row & 3);                                  \
      GLOAD16(Wb + (size_t)(gn0 + row) * IN_CH + (K0) + sc * 8,                \
              &lds_b[BUF][16 * wl][0]);                                        \
    }                                                                          \
  }

#define COMPUTE(BUF)                                                           \
  {                                                                            \
    const int l15 = lane & 15;                                                 \
    const int kb  = lane >> 4;                                                 \
    bf16x8 af[4], bfr[4];                                                      \
    _Pragma("unroll")                                                          \
    for (int i = 0; i < 4; i++) {                                              \
      const int row = wr * 64 + i * 16 + l15;                                  \
      const int c0  = (2 * kb) ^ (row & 7);                                    \
      const int c1  = (2 * kb + 1) ^ (row & 7);                                \
      f32x4 lo = *(const f32x4*)&lds_a[BUF][row][c0 * 4];                      \
      f32x4 hi = *(const f32x4*)&lds_a[BUF][row][c1 * 4];                      \
      union { unsigned int u[4]; bf16x8 v; } t;                                \
      t.u[0] = cvtpk_bf16(lo[0], lo[1]);                                       \
      t.u[1] = cvtpk_bf16(lo[2], lo[3]);                                       \
      t.u[2] = cvtpk_bf16(hi[0], hi[1]);                                       \
      t.u[3] = cvtpk_bf16(hi[2], hi[3]);                                       \
      af[i] = t.v;                                                             \
    }                                                                          \
    _Pragma("unroll")                                                          \
    for (int j = 0; j < 4; j++) {                                              \
      const int row = wc * 64 + j * 16 + l15;                                  \
      const int c   = kb ^ (row & 3);                                          \
      bfr[j] = *(const bf16x8*)&lds_b[BUF][row][c * 8];                        \
    }                                                                          \
    _Pragma("unroll")                                                          \
    for (int i = 0; i < 4; i++)                                                \
      _Pragma("unroll")                                                        \
      for (int j = 0; j < 4; j++)                                              \
        acc[i][j] = __builtin_amdgcn_mfma_f32_16x16x32_bf16(af[i], bfr[j],     \
                                                            acc[i][j], 0, 0, 0); \
  }

  STAGE(0, 0);
  __syncthreads();

  for (int ks = 0; ks < 32; ks += 2) {
    if (ks + 1 < 32) STAGE(1, (ks + 1) * 32);
    COMPUTE(0);
    __syncthreads();
    if (ks + 2 < 32) STAGE(0, (ks + 2) * 32);
    COMPUTE(1);
    __syncthreads();
  }
#undef STAGE
#undef COMPUTE

  // epilogue: C/D layout col = lane&15, row = (lane>>4)*4 + r
  float bj[4];
  #pragma unroll
  for (int j = 0; j < 4; j++)
    bj[j] = bias[gn0 + wc * 64 + j * 16 + (lane & 15)];

  #pragma unroll
  for (int i = 0; i < 4; i++) {
    const int grow_base = gm0 + wr * 64 + i * 16 + ((lane >> 4) << 2);
    #pragma unroll
    for (int r = 0; r < 4; r++) {
      const int grow = grow_base + r;
      if (grow < N_NODES) {
        #pragma unroll
        for (int j = 0; j < 4; j++) {
          const int gcol = gn0 + wc * 64 + j * 16 + (lane & 15);
          Hb[(size_t)grow * OUT_CH + gcol] = f2bf(acc[i][j][r] + bj[j]);
        }
      }
    }
  }
}

// per-block exclusive scan; local-excl to offsets, block total to blocksum
__global__ __launch_bounds__(256) void scan_block(const int* __restrict__ counts,
                                                  int* __restrict__ offsets,
                                                  int* __restrict__ blocksum) {
  __shared__ int wsum[4];
  const int tid = threadIdx.x, lane = tid & 63, wv = tid >> 6;
  const int i = blockIdx.x * 256 + tid;
  const int v = (i < N_NODES) ? counts[i] : 0;
  int s = v;
  #pragma unroll
  for (int off = 1; off < 64; off <<= 1) {
    int t = __shfl_up(s, off, 64);
    if (lane >= off) s += t;
  }
  if (lane == 63) wsum[wv] = s;
  __syncthreads();
  if (tid == 0) {
    int c = 0;
    #pragma unroll
    for (int k = 0; k < 4; k++) { int t = wsum[k]; wsum[k] = c; c += t; }
  }
  __syncthreads();
  const int excl = wsum[wv] + s - v;
  if (i < N_NODES) offsets[i] = excl;
  if (tid == 255) blocksum[blockIdx.x] = excl + v;
}

__global__ __launch_bounds__(256) void scan_sums(int* __restrict__ blocksum,
                                                 int* __restrict__ offsets) {
  __shared__ int wsum[4];
  const int tid = threadIdx.x, lane = tid & 63, wv = tid >> 6;
  const int v = (tid < NBLK) ? blocksum[tid] : 0;
  int s = v;
  #pragma unroll
  for (int off = 1; off < 64; off <<= 1) {
    int t = __shfl_up(s, off, 64);
    if (lane >= off) s += t;
  }
  if (lane == 63) wsum[wv] = s;
  __syncthreads();
  if (tid == 0) {
    int c = 0;
    #pragma unroll
    for (int k = 0; k < 4; k++) { int t = wsum[k]; wsum[k] = c; c += t; }
  }
  __syncthreads();
  const int excl = wsum[wv] + s - v;
  if (tid < NBLK) blocksum[tid] = excl;
  if (tid == 255) offsets[N_NODES] = excl;
}

__global__ __launch_bounds__(256) void finalize_offsets(int* __restrict__ offsets,
                                                        const int* __restrict__ blocksum,
                                                        int* __restrict__ cursor) {
  const int i = blockIdx.x * 256 + threadIdx.x;
  if (i < N_NODES) {
    const int off = offsets[i] + blocksum[i >> 8];
    offsets[i] = off;
    cursor[i] = off;
  }
}

__global__ __launch_bounds__(256) void fill_csr(const int* __restrict__ src,
                                                const int* __restrict__ tar,
                                                const float* __restrict__ ew,
                                                int* __restrict__ cursor,
                                                int2* __restrict__ edata) {
  int e = blockIdx.x * blockDim.x + threadIdx.x;
  if (e >= N_EDGES) return;
  const int t = tar[e];
  const int p = atomicAdd(&cursor[t], 1);
  edata[p] = make_int2(src[e], __float_as_int(ew[e]));
}

// one wave per node: OUT = sw*h_self + sum_e w_e * h_src
__global__ __launch_bounds__(256) void node_agg(
    const unsigned short* __restrict__ Hb, const int* __restrict__ offsets,
    const int2* __restrict__ edata, const float* __restrict__ sw,
    float* __restrict__ OUT)
{
  const int wid = (blockIdx.x * blockDim.x + threadIdx.x) >> 6;
  if (wid >= N_NODES) return;
  const int lane = threadIdx.x & 63;
  const int e0 = offsets[wid];
  const int e1 = offsets[wid + 1];

  float a0 = 0.f, a1 = 0.f, a2 = 0.f, a3 = 0.f;

  for (int base = e0; base < e1; base += 64) {
    const int avail = e1 - base;
    int2 d = make_int2(0, 0);
    if (lane < avail) d = edata[base + lane];
    const int n = (avail < 64) ? avail : 64;
    int j = 0;
    for (; j + 4 <= n; j += 4) {
      const int   s0 = __shfl(d.x, j, 64),     s1 = __shfl(d.x, j + 1, 64);
      const int   s2 = __shfl(d.x, j + 2, 64), s3 = __shfl(d.x, j + 3, 64);
      const float w0 = __int_as_float(__shfl(d.y, j, 64));
      const float w1 = __int_as_float(__shfl(d.y, j + 1, 64));
      const float w2 = __int_as_float(__shfl(d.y, j + 2, 64));
      const float w3 = __int_as_float(__shfl(d.y, j + 3, 64));
      const ushort4 h0 = *(const ushort4*)(Hb + (size_t)s0 * OUT_CH + lane * 4);
      const ushort4 h1 = *(const ushort4*)(Hb + (size_t)s1 * OUT_CH + lane * 4);
      const ushort4 h2 = *(const ushort4*)(Hb + (size_t)s2 * OUT_CH + lane * 4);
      const ushort4 h3 = *(const ushort4*)(Hb + (size_t)s3 * OUT_CH + lane * 4);
      a0 += w0 * bf2f(h0.x) + w1 * bf2f(h1.x) + w2 * bf2f(h2.x) + w3 * bf2f(h3.x);
      a1 += w0 * bf2f(h0.y) + w1 * bf2f(h1.y) + w2 * bf2f(h2.y) + w3 * bf2f(h3.y);
      a2 += w0 * bf2f(h0.z) + w1 * bf2f(h1.z) + w2 * bf2f(h2.z) + w3 * bf2f(h3.z);
      a3 += w0 * bf2f(h0.w) + w1 * bf2f(h1.w) + w2 * bf2f(h2.w) + w3 * bf2f(h3.w);
    }
    for (; j < n; j++) {
      const int   s = __shfl(d.x, j, 64);
      const float wgt = __int_as_float(__shfl(d.y, j, 64));
      const ushort4 h = *(const ushort4*)(Hb + (size_t)s * OUT_CH + lane * 4);
      a0 += wgt * bf2f(h.x); a1 += wgt * bf2f(h.y);
      a2 += wgt * bf2f(h.z); a3 += wgt * bf2f(h.w);
    }
  }

  const float swv = sw[wid];
  const ushort4 hs = *(const ushort4*)(Hb + (size_t)wid * OUT_CH + lane * 4);
  float4 o;
  o.x = a0 + swv * bf2f(hs.x);
  o.y = a1 + swv * bf2f(hs.y);
  o.z = a2 + swv * bf2f(hs.z);
  o.w = a3 + swv * bf2f(hs.w);
  *(float4*)(OUT + (size_t)wid * OUT_CH + lane * 4) = o;
}

extern "C" void kernel_launch(void* const* d_in, const int* in_sizes, int n_in,
                              void* d_out, int out_size, void* d_ws, size_t ws_size,
                              hipStream_t stream) {
  const float* x   = (const float*)d_in[0];
  const float* W   = (const float*)d_in[1];
  const float* b   = (const float*)d_in[2];
  const int*   src = (const int*)d_in[3];
  const int*   tar = (const int*)d_in[4];
  const float* ew  = (const float*)d_in[5];
  const float* sw  = (const float*)d_in[6];
  float* out = (float*)d_out;

  // ws: Wb 0.5MB | Hb 25.6MB | counts | offsets | cursor | blocksum | edata 6.4MB  (~33MB)
  char* ws = (char*)d_ws;
  size_t o = 0;
  unsigned short* Wb = (unsigned short*)(ws + o);
  o += (size_t)OUT_CH * IN_CH * 2;          o = (o + 255) & ~(size_t)255;
  unsigned short* Hb = (unsigned short*)(ws + o);
  o += (size_t)N_NODES * OUT_CH * 2;        o = (o + 255) & ~(size_t)255;
  int* counts   = (int*)(ws + o); o += (size_t)N_NODES * 4;       o = (o + 255) & ~(size_t)255;
  int* offsets  = (int*)(ws + o); o += (size_t)(N_NODES + 1) * 4; o = (o + 255) & ~(size_t)255;
  int* cursor   = (int*)(ws + o); o += (size_t)N_NODES * 4;       o = (o + 255) & ~(size_t)255;
  int* blocksum = (int*)(ws + o); o += (size_t)NBLK * 4;          o = (o + 255) & ~(size_t)255;
  int2* edata   = (int2*)(ws + o);

  hipMemsetAsync(counts, 0, (size_t)N_NODES * 4, stream);
  prep_hist<<<256 + (N_EDGES + 255) / 256, 256, 0, stream>>>(W, Wb, tar, counts);
  scan_block<<<NBLK, 256, 0, stream>>>(counts, offsets, blocksum);
  scan_sums<<<1, 256, 0, stream>>>(blocksum, offsets);
  finalize_offsets<<<NBLK, 256, 0, stream>>>(offsets, blocksum, cursor);
  fill_csr<<<(N_EDGES + 255) / 256, 256, 0, stream>>>(src, tar, ew, cursor, edata);

  dim3 g1((N_NODES + 127) / 128, OUT_CH / 128);
  gemm_proj<<<g1, 256, 0, stream>>>(x, Wb, b, Hb);

  const long long nthreads = (long long)N_NODES * 64;
  node_agg<<<(int)((nthreads + 255) / 256), 256, 0, stream>>>(Hb, offsets, edata, sw, out);
}